// Round 10
// baseline (414.275 us; speedup 1.0000x reference)
//
#include <hip/hip_runtime.h>

#define S_LEN 77
#define NHEAD 12
#define DHEAD 64
#define EMB   768
#define BATCH 512
#define MROWS (BATCH * S_LEN)   /* 39424 */
#define NQKV  (3 * EMB)         /* 2304  */
#define KDIM  768
#define NKT   (KDIM / 64)       /* 12 K-tiles of 64 */

typedef __attribute__((ext_vector_type(8))) short bf16x8;
typedef __attribute__((ext_vector_type(4))) float f32x4;

#define WAITV(n) asm volatile("s_waitcnt vmcnt(" #n ")" ::: "memory")
#define WAITL(n) asm volatile("s_waitcnt lgkmcnt(" #n ")" ::: "memory")
#define SB()     __builtin_amdgcn_sched_barrier(0)

__device__ __forceinline__ unsigned short f2bf(float f) {
  union { float f; unsigned int u; } v; v.f = f;
  unsigned int r = (v.u + 0x7fffu + ((v.u >> 16) & 1u)) >> 16;
  return (unsigned short)r;
}

__device__ __forceinline__ void gload_lds16(const void* g, void* l) {
  __builtin_amdgcn_global_load_lds((__attribute__((address_space(1))) void*)g,
                                   (__attribute__((address_space(3))) void*)l,
                                   16, 0, 0);
}

// ---------------- weights: transpose to [N][K] bf16 with COALESCED writes ----
__global__ void prep_weights(const float* __restrict__ wq, const float* __restrict__ wk,
                             const float* __restrict__ wv, const float* __restrict__ wo,
                             const float* __restrict__ bq, const float* __restrict__ bk,
                             const float* __restrict__ bv,
                             unsigned short* __restrict__ wqkvT,
                             unsigned short* __restrict__ woT,
                             float* __restrict__ bqkv) {
  const int i0 = blockIdx.x * blockDim.x + threadIdx.x;
  const int stride = gridDim.x * blockDim.x;
  const int KB = EMB / 8;   // 96 eight-wide k-blocks per row
  for (int idx = i0; idx < NQKV * KB; idx += stride) {
    int n = idx / KB, k0 = (idx - n * KB) * 8;
    const float* w; int c;
    if (n < EMB)          { w = wq; c = n; }
    else if (n < 2 * EMB) { w = wk; c = n - EMB; }
    else                  { w = wv; c = n - 2 * EMB; }
    bf16x8 o;
#pragma unroll
    for (int i = 0; i < 8; ++i) o[i] = (short)f2bf(w[(size_t)(k0 + i) * EMB + c]);
    *(bf16x8*)(wqkvT + (size_t)n * EMB + k0) = o;
  }
  for (int idx = i0; idx < EMB * KB; idx += stride) {
    int n = idx / KB, k0 = (idx - n * KB) * 8;
    bf16x8 o;
#pragma unroll
    for (int i = 0; i < 8; ++i) o[i] = (short)f2bf(wo[(size_t)(k0 + i) * EMB + n]);
    *(bf16x8*)(woT + (size_t)n * EMB + k0) = o;
  }
  for (int idx = i0; idx < NQKV; idx += stride) {
    bqkv[idx] = (idx < EMB) ? bq[idx]
              : (idx < 2 * EMB ? bk[idx - EMB] : bv[idx - 2 * EMB]);
  }
}

// ---------------- 256x256 8-phase-style GEMM ----------------
// MODE 0: A comes from x (fp32) — fused convert: reg-stage 8 x f32x4 at p0,
//         vmcnt(4)+cvt+ds_write_b128 at p2 into the idle LDS slot. C = bf16.
// MODE 1: A bf16 via gload_lds (round-5 path, unchanged). C = f32.
template <int MODE>
__global__ __launch_bounds__(512, 2) void gemm256(const unsigned short* __restrict__ A,
                                                  const float* __restrict__ Af,
                                                  const unsigned short* __restrict__ BT,
                                                  const float* __restrict__ bias,
                                                  void* __restrict__ Cout) {
  // slot s (s=0,1) at s*32768 shorts: A tile 256x64 at +0, B tile at +16384
  __shared__ unsigned short lds[2 * 32768];   // 128 KiB

  const int tid  = threadIdx.x;
  const int wave = tid >> 6;
  const int lane = tid & 63;
  const int wr = wave >> 2;        // 0..1  -> rows wr*128..+128
  const int wc = wave & 3;         // 0..3  -> cols wc*64..+64
  const int fr = lane & 15;
  const int fg = lane >> 4;        // 0..3

  // T1: bijective XCD swizzle (m204)
  const int ncol = gridDim.x;
  const int nwg  = gridDim.x * gridDim.y;
  const int orig = blockIdx.y * gridDim.x + blockIdx.x;
  const int q8   = nwg >> 3, r8 = nwg & 7;
  const int xcd  = orig & 7, off = orig >> 3;
  const int swz  = (xcd < r8 ? xcd * (q8 + 1) : r8 * (q8 + 1) + (xcd - r8) * q8) + off;
  const int brow = (swz / ncol) * 256;
  const int bcol = (swz % ncol) * 256;

  f32x4 acc[8][4] = {};

  const int grow = (wave >> 2) * 128 + (wave & 3) * 8 + (lane >> 3);
  const int srcc = (lane & 7) ^ ((lane >> 3) & 7);
  const unsigned short* gA = (MODE == 1) ? A + (size_t)(brow + grow) * KDIM + srcc * 8 : nullptr;
  const float*          gF = (MODE == 0) ? Af + (size_t)(brow + grow) * KDIM + srcc * 8 : nullptr;
  const unsigned short* gB = BT + (size_t)(bcol + grow) * KDIM + srcc * 8;
  const int wbase = (wave >> 2) * 8192 + (wave & 3) * 512;

  auto ALOAD = [&](int t, int j) {   // MODE 1 only
    gload_lds16(gA + (size_t)(j * 32) * KDIM + t * 64,
                lds + (t & 1) * 32768 + wbase + j * 2048);
  };
  auto BLOAD = [&](int t, int j) {
    gload_lds16(gB + (size_t)(j * 32) * KDIM + t * 64,
                lds + (t & 1) * 32768 + 16384 + wbase + j * 2048);
  };

  f32x4 areg[8];                     // MODE 0: in-flight fp32 A (32 VGPR)
#define AGLB(t)                                                                 \
  { _Pragma("unroll")                                                           \
    for (int j = 0; j < 4; ++j) {                                               \
      const float* p = gF + (size_t)(j * 32) * KDIM + (t) * 64;                 \
      areg[2 * j]     = *(const f32x4*)(p);                                     \
      areg[2 * j + 1] = *(const f32x4*)(p + 4);                                 \
    } }
#define AWRITE(t)                                                               \
  { _Pragma("unroll")                                                           \
    for (int j = 0; j < 4; ++j) {                                               \
      bf16x8 o;                                                                 \
      _Pragma("unroll")                                                         \
      for (int i = 0; i < 4; ++i) o[i]     = (short)f2bf(areg[2 * j][i]);       \
      _Pragma("unroll")                                                         \
      for (int i = 0; i < 4; ++i) o[4 + i] = (short)f2bf(areg[2 * j + 1][i]);   \
      *(bf16x8*)(lds + ((t) & 1) * 32768 + wbase + j * 2048 + lane * 8) = o;    \
    } }

  const int rsw = fr & 7;          // read-side XOR on the 16B chunk index

  // ---- prologue: stage tile 0 ----
  if (MODE == 0) {
    AGLB(0);                       // 8 fp32 loads (vm queue first)
    SB();
    #pragma unroll
    for (int j = 0; j < 4; ++j) BLOAD(0, j);
    WAITV(4); SB();                // drain the 8 A loads (B×4 still in flight)
    AWRITE(0);
    WAITL(0);                      // ds_writes visible before barrier
    WAITV(0);                      // B staged
    SB();
  } else {
    #pragma unroll
    for (int j = 0; j < 4; ++j) BLOAD(0, j);
    #pragma unroll
    for (int j = 0; j < 4; ++j) ALOAD(0, j);
    WAITV(2);
    SB();
  }
  __builtin_amdgcn_s_barrier();

  for (int t = 0; t < NKT; ++t) {
    const bool st = (t + 1 < NKT);             // stage tile t+1 this group
    const unsigned short* sb  = lds + (t & 1) * 32768;
    const unsigned short* sbB = sb + 16384;
    bf16x8 bfr[4][2];
    #pragma unroll
    for (int p = 0; p < 4; ++p) {
      // ---- ds_read: A quadrant (m = 2p, 2p+1), plus all B at p==0 ----
      if (p == 0) {
        #pragma unroll
        for (int n = 0; n < 4; ++n)
          #pragma unroll
          for (int kk = 0; kk < 2; ++kk)
            bfr[n][kk] = *(const bf16x8*)(sbB + (wc * 64 + n * 16 + fr) * 64 +
                                          (((kk * 4 + fg) ^ rsw) * 8));
      }
      bf16x8 afr[2][2];
      #pragma unroll
      for (int mi = 0; mi < 2; ++mi)
        #pragma unroll
        for (int kk = 0; kk < 2; ++kk)
          afr[mi][kk] = *(const bf16x8*)(sb + (wr * 128 + (2 * p + mi) * 16 + fr) * 64 +
                                         (((kk * 4 + fg) ^ rsw) * 8));
      // ---- staging issue ----
      if (MODE == 0) {
        if (p == 0 && st) {
          AGLB(t + 1);             // vm queue: [A x8 ...]
          SB();
          BLOAD(t + 1, 0); BLOAD(t + 1, 1); BLOAD(t + 1, 2); BLOAD(t + 1, 3);
        }
        if (p == 2 && st) {
          WAITV(4); SB();          // drain A x8 (B x4 left in flight)
          AWRITE(t + 1);           // slot (t+1)&1 is idle since tile t-1's end
        }
      } else {
        if (st) {
          if (p < 2) { BLOAD(t + 1, 2 * p);     BLOAD(t + 1, 2 * p + 1); }
          else       { ALOAD(t + 1, 2 * p - 4); ALOAD(t + 1, 2 * p - 3); }
        }
      }
      SB();
      __builtin_amdgcn_s_barrier();
      asm volatile("s_waitcnt lgkmcnt(0)" ::: "memory");
      SB();
      // ---- 16 MFMA ----
      __builtin_amdgcn_s_setprio(1);
      #pragma unroll
      for (int kk = 0; kk < 2; ++kk)
        #pragma unroll
        for (int mi = 0; mi < 2; ++mi)
          #pragma unroll
          for (int n = 0; n < 4; ++n)
            acc[2 * p + mi][n] = __builtin_amdgcn_mfma_f32_16x16x32_bf16(
                afr[mi][kk], bfr[n][kk], acc[2 * p + mi][n], 0, 0, 0);
      __builtin_amdgcn_s_setprio(0);
      SB();
      // ---- counted vmcnt (T4) ----
      if (MODE == 0) {
        if (p == 3 && st) { WAITV(0); }   // B gload_lds issued 3 phases ago
        if (p == 1 && !st) { WAITV(0); }
      } else {
        if (p == 1) { if (st) { WAITV(4); } else { WAITV(0); } }
        if (p == 3 && st) { WAITV(2); }
      }
      __builtin_amdgcn_s_barrier();
    }
  }
#undef AGLB
#undef AWRITE

  // epilogue: n innermost so both 32B halves of each 64B line store back-to-back
  float bvals[4];
#pragma unroll
  for (int n = 0; n < 4; ++n) bvals[n] = bias[bcol + wc * 64 + n * 16 + fr];
#pragma unroll
  for (int m = 0; m < 8; ++m) {
#pragma unroll
    for (int r = 0; r < 4; ++r) {
      const int row = brow + wr * 128 + m * 16 + fg * 4 + r;
#pragma unroll
      for (int n = 0; n < 4; ++n) {
        const int col = bcol + wc * 64 + n * 16 + fr;
        float v = acc[m][n][r] + bvals[n];
        if (MODE == 0) {
          if (col < EMB) v *= 0.125f;
          ((unsigned short*)Cout)[(size_t)row * NQKV + col] = f2bf(v);
        } else {
          ((float*)Cout)[(size_t)row * EMB + col] = v;
        }
      }
    }
  }
}

// ---------------- attention: one block per (b,h), 5 waves (16-row stripes) ----
// Q AND K fragments load directly from global (L2-hot); only V transposed
// through LDS; ONE __syncthreads before PV. LDS 30 KB -> 5 blocks/CU.
#define SV 104
__global__ __launch_bounds__(320) void attn_kernel(const unsigned short* __restrict__ qkv,
                                                   unsigned short* __restrict__ attn_out) {
  __shared__ unsigned short vT_lds[64 * SV];   // [d][t], stride 104
  __shared__ unsigned short p_lds[80 * SV];    // [s][t], stride 104

  const int tid  = threadIdx.x;
  const int wv_  = tid >> 6;   // stripe 0..4
  const int lane = tid & 63;
  const int fr = lane & 15;
  const int fg = lane >> 4;

  const int bh = blockIdx.x;
  const int b  = bh / NHEAD;
  const int h  = bh - b * NHEAD;

  const size_t base = (size_t)b * S_LEN * NQKV + (size_t)h * DHEAD;

  // Q fragments (this stripe's rows) + K fragments (all t rows) direct to regs
  bf16x8 qfr[2], kfr[5][2];
  {
    const int srow = wv_ * 16 + fr;
    const int qs = (srow < S_LEN) ? srow : 0;   // clamp: pad rows discarded later
    const unsigned short* qg = qkv + base + (size_t)qs * NQKV + fg * 8;
    qfr[0] = *(const bf16x8*)(qg);
    qfr[1] = *(const bf16x8*)(qg + 32);
    const unsigned short* kg = qkv + base + EMB + fg * 8;
#pragma unroll
    for (int n = 0; n < 5; ++n)
#pragma unroll
      for (int kk = 0; kk < 2; ++kk)
        kfr[n][kk] = *(const bf16x8*)(kg + (size_t)(n * 16 + fr) * NQKV + kk * 32);
  }

  // zero ONLY the pad strips PV multiplies by nonzero values
  for (int i = tid; i < 64 * 19; i += 320) {
    int d = i / 19, c = 77 + (i - d * 19);
    vT_lds[d * SV + c] = 0;
  }
  for (int i = tid; i < 80 * 16; i += 320) {
    int s = i >> 4, c = 80 + (i & 15);
    p_lds[s * SV + c] = 0;
  }

  // stage transposed V (strips above are disjoint from these writes)
  for (int idx = tid; idx < S_LEN * 32; idx += 320) {
    int s = idx >> 5, c = idx & 31;
    unsigned int vx = *(const unsigned int*)(qkv + base + (size_t)s * NQKV + 2 * EMB + c * 2);
    vT_lds[(c * 2 + 0) * SV + s] = (unsigned short)(vx & 0xffffu);
    vT_lds[(c * 2 + 1) * SV + s] = (unsigned short)(vx >> 16);
  }

  // QK^T : scores[s][t] from registers only — no barrier needed
  f32x4 sc[5];
#pragma unroll
  for (int n = 0; n < 5; ++n) sc[n] = (f32x4){0.f, 0.f, 0.f, 0.f};
#pragma unroll
  for (int kk = 0; kk < 2; ++kk)
#pragma unroll
    for (int n = 0; n < 5; ++n)
      sc[n] = __builtin_amdgcn_mfma_f32_16x16x32_bf16(qfr[kk], kfr[n][kk], sc[n], 0, 0, 0);

  // causal softmax; rows per lane: s = wv_*16 + fg*4 + r, cols t = n*16 + fr
  float mrow[4], ssum[4];
#pragma unroll
  for (int r = 0; r < 4; ++r) {
    const int s_loc = wv_ * 16 + fg * 4 + r;
    float mx = -1e30f;
#pragma unroll
    for (int n = 0; n < 5; ++n) {
      const int t = n * 16 + fr;
      float val = ((t <= s_loc) && (t < S_LEN)) ? sc[n][r] : -1e30f;
      sc[n][r] = val;
      mx = fmaxf(mx, val);
    }
    mrow[r] = mx;
  }
#pragma unroll
  for (int off = 1; off < 16; off <<= 1)
#pragma unroll
    for (int r = 0; r < 4; ++r)
      mrow[r] = fmaxf(mrow[r], __shfl_xor(mrow[r], off, 64));
#pragma unroll
  for (int r = 0; r < 4; ++r) {
    float sm = 0.f;
#pragma unroll
    for (int n = 0; n < 5; ++n) {
      float p = __expf(sc[n][r] - mrow[r]);
      sc[n][r] = p;
      sm += p;
    }
    ssum[r] = sm;
  }
#pragma unroll
  for (int off = 1; off < 16; off <<= 1)
#pragma unroll
    for (int r = 0; r < 4; ++r)
      ssum[r] += __shfl_xor(ssum[r], off, 64);

#pragma unroll
  for (int r = 0; r < 4; ++r) {
    const int srow = wv_ * 16 + fg * 4 + r;
    const float inv = 1.0f / ssum[r];
#pragma unroll
    for (int n = 0; n < 5; ++n)
      p_lds[srow * SV + n * 16 + fr] = f2bf(sc[n][r] * inv);
  }
  // ONE barrier: vT (cross-wave) + p (wave-local) both complete before PV
  __syncthreads();

  // PV : out[s][d] = sum_t p[s][t] * v[t][d], t padded to 96 (pad strips zero)
  f32x4 o[4];
#pragma unroll
  for (int n = 0; n < 4; ++n) o[n] = (f32x4){0.f, 0.f, 0.f, 0.f};
#pragma unroll
  for (int kk = 0; kk < 96; kk += 32) {
    bf16x8 afr = *(const bf16x8*)(p_lds + (wv_ * 16 + fr) * SV + kk + fg * 8);
#pragma unroll
    for (int n = 0; n < 4; ++n) {
      bf16x8 bfr = *(const bf16x8*)(vT_lds + (n * 16 + fr) * SV + kk + fg * 8);
      o[n] = __builtin_amdgcn_mfma_f32_16x16x32_bf16(afr, bfr, o[n], 0, 0, 0);
    }
  }

  const size_t obase = (size_t)b * S_LEN * EMB + (size_t)h * DHEAD;
#pragma unroll
  for (int r = 0; r < 4; ++r) {
    const int srow = wv_ * 16 + fg * 4 + r;
    if (srow < S_LEN) {
#pragma unroll
      for (int n = 0; n < 4; ++n)
        attn_out[obase + (size_t)srow * EMB + n * 16 + fr] = f2bf(o[n][r]);
    }
  }
}

extern "C" void kernel_launch(void* const* d_in, const int* in_sizes, int n_in,
                              void* d_out, int out_size, void* d_ws, size_t ws_size,
                              hipStream_t stream) {
  const float* x  = (const float*)d_in[0];
  const float* wq = (const float*)d_in[1];
  const float* bq = (const float*)d_in[2];
  const float* wk = (const float*)d_in[3];
  const float* bk = (const float*)d_in[4];
  const float* wv = (const float*)d_in[5];
  const float* bv = (const float*)d_in[6];
  const float* wo = (const float*)d_in[7];
  const float* bo = (const float*)d_in[8];
  (void)in_sizes; (void)n_in; (void)out_size; (void)ws_size;

  char* ws = (char*)d_ws;
  // layout (bytes) — x_bf slot retired (cvt fused into QKV GEMM):
  unsigned short* wqkvT  = (unsigned short*)(ws + 60555264ULL);    // 2304*768 bf16 =  3,538,944
  unsigned short* woT    = (unsigned short*)(ws + 64094208ULL);    // 768*768 bf16  =  1,179,648
  float*          bqkv   = (float*)         (ws + 65273856ULL);    // 2304 f32      =      9,216
  unsigned short* qkv    = (unsigned short*)(ws + 65283072ULL);    // M*2304 bf16   = 181,665,792
  unsigned short* attn_o = (unsigned short*)(ws + 246948864ULL);   // M*768 bf16    = 60,555,264

  prep_weights<<<1024, 256, 0, stream>>>(wq, wk, wv, wo, bq, bk, bv, wqkvT, woT, bqkv);
  gemm256<0><<<dim3(NQKV / 256, MROWS / 256), 512, 0, stream>>>(nullptr, x, wqkvT, bqkv, qkv);
  attn_kernel<<<BATCH * NHEAD, 320, 0, stream>>>(qkv, attn_o);
  gemm256<1><<<dim3(EMB / 256, MROWS / 256), 512, 0, stream>>>(attn_o, nullptr, woT, bo, d_out);
}

// Round 11
// 363.979 us; speedup vs baseline: 1.1382x; 1.1382x over previous
//
#include <hip/hip_runtime.h>

#define S_LEN 77
#define NHEAD 12
#define DHEAD 64
#define EMB   768
#define BATCH 512
#define MROWS (BATCH * S_LEN)   /* 39424 */
#define NQKV  (3 * EMB)         /* 2304  */
#define KDIM  768
#define NKT   (KDIM / 64)       /* 12 K-tiles of 64 */

typedef __attribute__((ext_vector_type(8))) short bf16x8;
typedef __attribute__((ext_vector_type(4))) float f32x4;

#define WAITV(n) asm volatile("s_waitcnt vmcnt(" #n ")" ::: "memory")
#define WAITL(n) asm volatile("s_waitcnt lgkmcnt(" #n ")" ::: "memory")

__device__ __forceinline__ unsigned short f2bf(float f) {
  union { float f; unsigned int u; } v; v.f = f;
  unsigned int r = (v.u + 0x7fffu + ((v.u >> 16) & 1u)) >> 16;
  return (unsigned short)r;
}

__device__ __forceinline__ void gload_lds16(const void* g, void* l) {
  __builtin_amdgcn_global_load_lds((__attribute__((address_space(1))) void*)g,
                                   (__attribute__((address_space(3))) void*)l,
                                   16, 0, 0);
}

// ---------------- fused: x fp32->bf16 (BW-bound) + weight transpose + bias ----
// Independent elementwise workloads concatenated as grid-stride loops; the
// small L2-resident weight work overlaps the HBM-bound x conversion.
__global__ void prep_all(const float4* __restrict__ x4, ushort4* __restrict__ xbf4,
                         const float* __restrict__ wq, const float* __restrict__ wk,
                         const float* __restrict__ wv, const float* __restrict__ wo,
                         const float* __restrict__ bq, const float* __restrict__ bk,
                         const float* __restrict__ bv,
                         unsigned short* __restrict__ wqkvT,
                         unsigned short* __restrict__ woT,
                         float* __restrict__ bqkv) {
  const int i0 = blockIdx.x * blockDim.x + threadIdx.x;
  const int stride = gridDim.x * blockDim.x;
  const int KB = EMB / 8;   // 96 eight-wide k-blocks per row
  // 1) weight transpose qkv: coalesced 16B stores, strided L2-hot reads
  for (int idx = i0; idx < NQKV * KB; idx += stride) {
    int n = idx / KB, k0 = (idx - n * KB) * 8;
    const float* w; int c;
    if (n < EMB)          { w = wq; c = n; }
    else if (n < 2 * EMB) { w = wk; c = n - EMB; }
    else                  { w = wv; c = n - 2 * EMB; }
    bf16x8 o;
#pragma unroll
    for (int i = 0; i < 8; ++i) o[i] = (short)f2bf(w[(size_t)(k0 + i) * EMB + c]);
    *(bf16x8*)(wqkvT + (size_t)n * EMB + k0) = o;
  }
  // 2) weight transpose wo
  for (int idx = i0; idx < EMB * KB; idx += stride) {
    int n = idx / KB, k0 = (idx - n * KB) * 8;
    bf16x8 o;
#pragma unroll
    for (int i = 0; i < 8; ++i) o[i] = (short)f2bf(wo[(size_t)(k0 + i) * EMB + n]);
    *(bf16x8*)(woT + (size_t)n * EMB + k0) = o;
  }
  // 3) fused bias
  for (int idx = i0; idx < NQKV; idx += stride) {
    bqkv[idx] = (idx < EMB) ? bq[idx]
              : (idx < 2 * EMB ? bk[idx - EMB] : bv[idx - 2 * EMB]);
  }
  // 4) x fp32 -> bf16 (the big one: 121 MB read + 60.6 MB write)
  for (int i = i0; i < MROWS * EMB / 4; i += stride) {
    float4 v = x4[i];
    ushort4 o;
    o.x = f2bf(v.x); o.y = f2bf(v.y); o.z = f2bf(v.z); o.w = f2bf(v.w);
    xbf4[i] = o;
  }
}

// ---------------- 256x256 8-phase-style GEMM (round-5/9 version, known-good) ----
// MODE 0: C = bf16( (A*B + bias) * (col<768 ? 0.125 : 1) ), stride NQKV
// MODE 1: C = f32 ( A*B + bias ), stride EMB
template <int MODE>
__global__ __launch_bounds__(512, 2) void gemm256(const unsigned short* __restrict__ A,
                                                  const unsigned short* __restrict__ BT,
                                                  const float* __restrict__ bias,
                                                  void* __restrict__ Cout) {
  // slot s (s=0,1) at s*32768 shorts: A tile 256x64 at +0, B tile at +16384
  __shared__ unsigned short lds[2 * 32768];   // 128 KiB

  const int tid  = threadIdx.x;
  const int wave = tid >> 6;
  const int lane = tid & 63;
  const int wr = wave >> 2;        // 0..1  -> rows wr*128..+128
  const int wc = wave & 3;         // 0..3  -> cols wc*64..+64
  const int fr = lane & 15;
  const int fg = lane >> 4;        // 0..3

  // T1: bijective XCD swizzle (m204)
  const int ncol = gridDim.x;
  const int nwg  = gridDim.x * gridDim.y;
  const int orig = blockIdx.y * gridDim.x + blockIdx.x;
  const int q8   = nwg >> 3, r8 = nwg & 7;
  const int xcd  = orig & 7, off = orig >> 3;
  const int swz  = (xcd < r8 ? xcd * (q8 + 1) : r8 * (q8 + 1) + (xcd - r8) * q8) + off;
  const int brow = (swz / ncol) * 256;
  const int bcol = (swz % ncol) * 256;

  f32x4 acc[8][4] = {};

  const int grow = (wave >> 2) * 128 + (wave & 3) * 8 + (lane >> 3);
  const int srcc = (lane & 7) ^ ((lane >> 3) & 7);
  const unsigned short* gA = A  + (size_t)(brow + grow) * KDIM + srcc * 8;
  const unsigned short* gB = BT + (size_t)(bcol + grow) * KDIM + srcc * 8;
  const int wbase = (wave >> 2) * 8192 + (wave & 3) * 512;

  auto ALOAD = [&](int t, int j) {
    gload_lds16(gA + (size_t)(j * 32) * KDIM + t * 64,
                lds + (t & 1) * 32768 + wbase + j * 2048);
  };
  auto BLOAD = [&](int t, int j) {
    gload_lds16(gB + (size_t)(j * 32) * KDIM + t * 64,
                lds + (t & 1) * 32768 + 16384 + wbase + j * 2048);
  };

  const int rsw = fr & 7;          // read-side XOR on the 16B chunk index

  // prologue: stage tile 0 fully (B rounds then A rounds), wait all but A2,A3
  #pragma unroll
  for (int j = 0; j < 4; ++j) BLOAD(0, j);
  #pragma unroll
  for (int j = 0; j < 4; ++j) ALOAD(0, j);
  WAITV(2);
  __builtin_amdgcn_sched_barrier(0);
  __builtin_amdgcn_s_barrier();

  for (int t = 0; t < NKT; ++t) {
    const bool st = (t + 1 < NKT);             // stage tile t+1 this group
    const unsigned short* sb  = lds + (t & 1) * 32768;
    const unsigned short* sbB = sb + 16384;
    bf16x8 bfr[4][2];
    #pragma unroll
    for (int p = 0; p < 4; ++p) {
      // ---- ds_read: A quadrant (m = 2p, 2p+1), plus all B at p==0 ----
      if (p == 0) {
        #pragma unroll
        for (int n = 0; n < 4; ++n)
          #pragma unroll
          for (int kk = 0; kk < 2; ++kk)
            bfr[n][kk] = *(const bf16x8*)(sbB + (wc * 64 + n * 16 + fr) * 64 +
                                          (((kk * 4 + fg) ^ rsw) * 8));
      }
      bf16x8 afr[2][2];
      #pragma unroll
      for (int mi = 0; mi < 2; ++mi)
        #pragma unroll
        for (int kk = 0; kk < 2; ++kk)
          afr[mi][kk] = *(const bf16x8*)(sb + (wr * 128 + (2 * p + mi) * 16 + fr) * 64 +
                                         (((kk * 4 + fg) ^ rsw) * 8));
      // ---- stage 2 loads for tile t+1: p0:B01 p1:B23 p2:A01 p3:A23 ----
      if (st) {
        if (p < 2) { BLOAD(t + 1, 2 * p);     BLOAD(t + 1, 2 * p + 1); }
        else       { ALOAD(t + 1, 2 * p - 4); ALOAD(t + 1, 2 * p - 3); }
      }
      __builtin_amdgcn_sched_barrier(0);
      __builtin_amdgcn_s_barrier();
      asm volatile("s_waitcnt lgkmcnt(0)" ::: "memory");
      __builtin_amdgcn_sched_barrier(0);
      // ---- 16 MFMA ----
      __builtin_amdgcn_s_setprio(1);
      #pragma unroll
      for (int kk = 0; kk < 2; ++kk)
        #pragma unroll
        for (int mi = 0; mi < 2; ++mi)
          #pragma unroll
          for (int n = 0; n < 4; ++n)
            acc[2 * p + mi][n] = __builtin_amdgcn_mfma_f32_16x16x32_bf16(
                afr[mi][kk], bfr[n][kk], acc[2 * p + mi][n], 0, 0, 0);
      __builtin_amdgcn_s_setprio(0);
      __builtin_amdgcn_sched_barrier(0);
      // ---- counted vmcnt (T4): never drain to 0 while staging ----
      if (p == 1) { if (st) { WAITV(4); } else { WAITV(0); } }
      if (p == 3 && st) { WAITV(2); }
      __builtin_amdgcn_s_barrier();
    }
  }

  // epilogue: n innermost so both 32B halves of each 64B line store back-to-back
  float bvals[4];
#pragma unroll
  for (int n = 0; n < 4; ++n) bvals[n] = bias[bcol + wc * 64 + n * 16 + fr];
#pragma unroll
  for (int m = 0; m < 8; ++m) {
#pragma unroll
    for (int r = 0; r < 4; ++r) {
      const int row = brow + wr * 128 + m * 16 + fg * 4 + r;
#pragma unroll
      for (int n = 0; n < 4; ++n) {
        const int col = bcol + wc * 64 + n * 16 + fr;
        float v = acc[m][n][r] + bvals[n];
        if (MODE == 0) {
          if (col < EMB) v *= 0.125f;
          ((unsigned short*)Cout)[(size_t)row * NQKV + col] = f2bf(v);
        } else {
          ((float*)Cout)[(size_t)row * EMB + col] = v;
        }
      }
    }
  }
}

// ---------------- attention: one block per (b,h), 5 waves (16-row stripes) ----
// Q AND K fragments load directly from global (L2/L3-hot); only V transposed
// through LDS; ONE __syncthreads before PV. LDS 30 KB -> 5 blocks/CU.
#define SV 104
__global__ __launch_bounds__(320) void attn_kernel(const unsigned short* __restrict__ qkv,
                                                   unsigned short* __restrict__ attn_out) {
  __shared__ unsigned short vT_lds[64 * SV];   // [d][t], stride 104
  __shared__ unsigned short p_lds[80 * SV];    // [s][t], stride 104

  const int tid  = threadIdx.x;
  const int wv_  = tid >> 6;   // stripe 0..4
  const int lane = tid & 63;
  const int fr = lane & 15;
  const int fg = lane >> 4;

  const int bh = blockIdx.x;
  const int b  = bh / NHEAD;
  const int h  = bh - b * NHEAD;

  const size_t base = (size_t)b * S_LEN * NQKV + (size_t)h * DHEAD;

  // Q fragments (this stripe's rows) + K fragments (all t rows) direct to regs
  bf16x8 qfr[2], kfr[5][2];
  {
    const int srow = wv_ * 16 + fr;
    const int qs = (srow < S_LEN) ? srow : 0;   // clamp: pad rows discarded later
    const unsigned short* qg = qkv + base + (size_t)qs * NQKV + fg * 8;
    qfr[0] = *(const bf16x8*)(qg);
    qfr[1] = *(const bf16x8*)(qg + 32);
    const unsigned short* kg = qkv + base + EMB + fg * 8;
#pragma unroll
    for (int n = 0; n < 5; ++n)
#pragma unroll
      for (int kk = 0; kk < 2; ++kk)
        kfr[n][kk] = *(const bf16x8*)(kg + (size_t)(n * 16 + fr) * NQKV + kk * 32);
  }

  // zero ONLY the pad strips PV multiplies by nonzero values
  for (int i = tid; i < 64 * 19; i += 320) {
    int d = i / 19, c = 77 + (i - d * 19);
    vT_lds[d * SV + c] = 0;
  }
  for (int i = tid; i < 80 * 16; i += 320) {
    int s = i >> 4, c = 80 + (i & 15);
    p_lds[s * SV + c] = 0;
  }

  // stage transposed V (strips above are disjoint from these writes)
  for (int idx = tid; idx < S_LEN * 32; idx += 320) {
    int s = idx >> 5, c = idx & 31;
    unsigned int vx = *(const unsigned int*)(qkv + base + (size_t)s * NQKV + 2 * EMB + c * 2);
    vT_lds[(c * 2 + 0) * SV + s] = (unsigned short)(vx & 0xffffu);
    vT_lds[(c * 2 + 1) * SV + s] = (unsigned short)(vx >> 16);
  }

  // QK^T : scores[s][t] from registers only — no barrier needed
  f32x4 sc[5];
#pragma unroll
  for (int n = 0; n < 5; ++n) sc[n] = (f32x4){0.f, 0.f, 0.f, 0.f};
#pragma unroll
  for (int kk = 0; kk < 2; ++kk)
#pragma unroll
    for (int n = 0; n < 5; ++n)
      sc[n] = __builtin_amdgcn_mfma_f32_16x16x32_bf16(qfr[kk], kfr[n][kk], sc[n], 0, 0, 0);

  // causal softmax; rows per lane: s = wv_*16 + fg*4 + r, cols t = n*16 + fr
  float mrow[4], ssum[4];
#pragma unroll
  for (int r = 0; r < 4; ++r) {
    const int s_loc = wv_ * 16 + fg * 4 + r;
    float mx = -1e30f;
#pragma unroll
    for (int n = 0; n < 5; ++n) {
      const int t = n * 16 + fr;
      float val = ((t <= s_loc) && (t < S_LEN)) ? sc[n][r] : -1e30f;
      sc[n][r] = val;
      mx = fmaxf(mx, val);
    }
    mrow[r] = mx;
  }
#pragma unroll
  for (int off = 1; off < 16; off <<= 1)
#pragma unroll
    for (int r = 0; r < 4; ++r)
      mrow[r] = fmaxf(mrow[r], __shfl_xor(mrow[r], off, 64));
#pragma unroll
  for (int r = 0; r < 4; ++r) {
    float sm = 0.f;
#pragma unroll
    for (int n = 0; n < 5; ++n) {
      float p = __expf(sc[n][r] - mrow[r]);
      sc[n][r] = p;
      sm += p;
    }
    ssum[r] = sm;
  }
#pragma unroll
  for (int off = 1; off < 16; off <<= 1)
#pragma unroll
    for (int r = 0; r < 4; ++r)
      ssum[r] += __shfl_xor(ssum[r], off, 64);

#pragma unroll
  for (int r = 0; r < 4; ++r) {
    const int srow = wv_ * 16 + fg * 4 + r;
    const float inv = 1.0f / ssum[r];
#pragma unroll
    for (int n = 0; n < 5; ++n)
      p_lds[srow * SV + n * 16 + fr] = f2bf(sc[n][r] * inv);
  }
  // ONE barrier: vT (cross-wave) + p (wave-local) both complete before PV
  __syncthreads();

  // PV : out[s][d] = sum_t p[s][t] * v[t][d], t padded to 96 (pad strips zero)
  f32x4 o[4];
#pragma unroll
  for (int n = 0; n < 4; ++n) o[n] = (f32x4){0.f, 0.f, 0.f, 0.f};
#pragma unroll
  for (int kk = 0; kk < 96; kk += 32) {
    bf16x8 afr = *(const bf16x8*)(p_lds + (wv_ * 16 + fr) * SV + kk + fg * 8);
#pragma unroll
    for (int n = 0; n < 4; ++n) {
      bf16x8 bfr = *(const bf16x8*)(vT_lds + (n * 16 + fr) * SV + kk + fg * 8);
      o[n] = __builtin_amdgcn_mfma_f32_16x16x32_bf16(afr, bfr, o[n], 0, 0, 0);
    }
  }

  const size_t obase = (size_t)b * S_LEN * EMB + (size_t)h * DHEAD;
#pragma unroll
  for (int r = 0; r < 4; ++r) {
    const int srow = wv_ * 16 + fg * 4 + r;
    if (srow < S_LEN) {
#pragma unroll
      for (int n = 0; n < 4; ++n)
        attn_out[obase + (size_t)srow * EMB + n * 16 + fr] = f2bf(o[n][r]);
    }
  }
}

extern "C" void kernel_launch(void* const* d_in, const int* in_sizes, int n_in,
                              void* d_out, int out_size, void* d_ws, size_t ws_size,
                              hipStream_t stream) {
  const float* x  = (const float*)d_in[0];
  const float* wq = (const float*)d_in[1];
  const float* bq = (const float*)d_in[2];
  const float* wk = (const float*)d_in[3];
  const float* bk = (const float*)d_in[4];
  const float* wv = (const float*)d_in[5];
  const float* bv = (const float*)d_in[6];
  const float* wo = (const float*)d_in[7];
  const float* bo = (const float*)d_in[8];
  (void)in_sizes; (void)n_in; (void)out_size; (void)ws_size;

  char* ws = (char*)d_ws;
  // layout (bytes):
  unsigned short* x_bf   = (unsigned short*)(ws);                  // M*E bf16      = 60,555,264
  unsigned short* wqkvT  = (unsigned short*)(ws + 60555264ULL);    // 2304*768 bf16 =  3,538,944
  unsigned short* woT    = (unsigned short*)(ws + 64094208ULL);    // 768*768 bf16  =  1,179,648
  float*          bqkv   = (float*)         (ws + 65273856ULL);    // 2304 f32      =      9,216
  unsigned short* qkv    = (unsigned short*)(ws + 65283072ULL);    // M*2304 bf16   = 181,665,792
  unsigned short* attn_o = (unsigned short*)(ws + 246948864ULL);   // M*768 bf16    = 60,555,264

  prep_all<<<2048, 256, 0, stream>>>((const float4*)x, (ushort4*)x_bf,
                                     wq, wk, wv, wo, bq, bk, bv, wqkvT, woT, bqkv);
  gemm256<0><<<dim3(NQKV / 256, MROWS / 256), 512, 0, stream>>>(x_bf, wqkvT, bqkv, qkv);
  attn_kernel<<<BATCH * NHEAD, 320, 0, stream>>>(qkv, attn_o);
  gemm256<1><<<dim3(EMB / 256, MROWS / 256), 512, 0, stream>>>(attn_o, woT, bo, d_out);
}

// Round 12
// 361.916 us; speedup vs baseline: 1.1447x; 1.0057x over previous
//
#include <hip/hip_runtime.h>

#define S_LEN 77
#define NHEAD 12
#define DHEAD 64
#define EMB   768
#define BATCH 512
#define MROWS (BATCH * S_LEN)   /* 39424 */
#define NQKV  (3 * EMB)         /* 2304  */
#define KDIM  768
#define NKT   (KDIM / 64)       /* 12 K-tiles of 64 */
#define SECSZ (BATCH * NHEAD * S_LEN * DHEAD)   /* 30,277,632 shorts per Q/K/V section */

typedef __attribute__((ext_vector_type(8))) short bf16x8;
typedef __attribute__((ext_vector_type(4))) float f32x4;

#define WAITV(n) asm volatile("s_waitcnt vmcnt(" #n ")" ::: "memory")
#define WAITL(n) asm volatile("s_waitcnt lgkmcnt(" #n ")" ::: "memory")

__device__ __forceinline__ unsigned short f2bf(float f) {
  union { float f; unsigned int u; } v; v.f = f;
  unsigned int r = (v.u + 0x7fffu + ((v.u >> 16) & 1u)) >> 16;
  return (unsigned short)r;
}

__device__ __forceinline__ void gload_lds16(const void* g, void* l) {
  __builtin_amdgcn_global_load_lds((__attribute__((address_space(1))) void*)g,
                                   (__attribute__((address_space(3))) void*)l,
                                   16, 0, 0);
}

// ---------------- fused: x fp32->bf16 + weight transpose + bias ----------------
__global__ void prep_all(const float4* __restrict__ x4, ushort4* __restrict__ xbf4,
                         const float* __restrict__ wq, const float* __restrict__ wk,
                         const float* __restrict__ wv, const float* __restrict__ wo,
                         const float* __restrict__ bq, const float* __restrict__ bk,
                         const float* __restrict__ bv,
                         unsigned short* __restrict__ wqkvT,
                         unsigned short* __restrict__ woT,
                         float* __restrict__ bqkv) {
  const int i0 = blockIdx.x * blockDim.x + threadIdx.x;
  const int stride = gridDim.x * blockDim.x;
  const int KB = EMB / 8;   // 96 eight-wide k-blocks per row
  for (int idx = i0; idx < NQKV * KB; idx += stride) {
    int n = idx / KB, k0 = (idx - n * KB) * 8;
    const float* w; int c;
    if (n < EMB)          { w = wq; c = n; }
    else if (n < 2 * EMB) { w = wk; c = n - EMB; }
    else                  { w = wv; c = n - 2 * EMB; }
    bf16x8 o;
#pragma unroll
    for (int i = 0; i < 8; ++i) o[i] = (short)f2bf(w[(size_t)(k0 + i) * EMB + c]);
    *(bf16x8*)(wqkvT + (size_t)n * EMB + k0) = o;
  }
  for (int idx = i0; idx < EMB * KB; idx += stride) {
    int n = idx / KB, k0 = (idx - n * KB) * 8;
    bf16x8 o;
#pragma unroll
    for (int i = 0; i < 8; ++i) o[i] = (short)f2bf(wo[(size_t)(k0 + i) * EMB + n]);
    *(bf16x8*)(woT + (size_t)n * EMB + k0) = o;
  }
  for (int idx = i0; idx < NQKV; idx += stride) {
    bqkv[idx] = (idx < EMB) ? bq[idx]
              : (idx < 2 * EMB ? bk[idx - EMB] : bv[idx - 2 * EMB]);
  }
  for (int i = i0; i < MROWS * EMB / 4; i += stride) {
    float4 v = x4[i];
    ushort4 o;
    o.x = f2bf(v.x); o.y = f2bf(v.y); o.z = f2bf(v.z); o.w = f2bf(v.w);
    xbf4[i] = o;
  }
}

// ---------------- 256x256 8-phase-style GEMM (round-5 loop, known-good) ----
// MODE 0: C -> head-major sections: sec(Q/K/V)[bh][s][d], Q scaled 0.125, bf16.
//         Each wave's 64-col span is exactly one head -> sec/h wave-uniform.
// MODE 1: C = f32 ( A*B + bias ), stride EMB (row-major, for d_out)
template <int MODE>
__global__ __launch_bounds__(512, 2) void gemm256(const unsigned short* __restrict__ A,
                                                  const unsigned short* __restrict__ BT,
                                                  const float* __restrict__ bias,
                                                  void* __restrict__ Cout) {
  __shared__ unsigned short lds[2 * 32768];   // 128 KiB

  const int tid  = threadIdx.x;
  const int wave = tid >> 6;
  const int lane = tid & 63;
  const int wr = wave >> 2;        // 0..1  -> rows wr*128..+128
  const int wc = wave & 3;         // 0..3  -> cols wc*64..+64
  const int fr = lane & 15;
  const int fg = lane >> 4;        // 0..3

  // T1: bijective XCD swizzle (m204)
  const int ncol = gridDim.x;
  const int nwg  = gridDim.x * gridDim.y;
  const int orig = blockIdx.y * gridDim.x + blockIdx.x;
  const int q8   = nwg >> 3, r8 = nwg & 7;
  const int xcd  = orig & 7, off = orig >> 3;
  const int swz  = (xcd < r8 ? xcd * (q8 + 1) : r8 * (q8 + 1) + (xcd - r8) * q8) + off;
  const int brow = (swz / ncol) * 256;
  const int bcol = (swz % ncol) * 256;

  f32x4 acc[8][4] = {};

  const int grow = (wave >> 2) * 128 + (wave & 3) * 8 + (lane >> 3);
  const int srcc = (lane & 7) ^ ((lane >> 3) & 7);
  const unsigned short* gA = A  + (size_t)(brow + grow) * KDIM + srcc * 8;
  const unsigned short* gB = BT + (size_t)(bcol + grow) * KDIM + srcc * 8;
  const int wbase = (wave >> 2) * 8192 + (wave & 3) * 512;

  auto ALOAD = [&](int t, int j) {
    gload_lds16(gA + (size_t)(j * 32) * KDIM + t * 64,
                lds + (t & 1) * 32768 + wbase + j * 2048);
  };
  auto BLOAD = [&](int t, int j) {
    gload_lds16(gB + (size_t)(j * 32) * KDIM + t * 64,
                lds + (t & 1) * 32768 + 16384 + wbase + j * 2048);
  };

  const int rsw = fr & 7;          // read-side XOR on the 16B chunk index

  // prologue: stage tile 0 fully (B rounds then A rounds), wait all but A2,A3
  #pragma unroll
  for (int j = 0; j < 4; ++j) BLOAD(0, j);
  #pragma unroll
  for (int j = 0; j < 4; ++j) ALOAD(0, j);
  WAITV(2);
  __builtin_amdgcn_sched_barrier(0);
  __builtin_amdgcn_s_barrier();

  for (int t = 0; t < NKT; ++t) {
    const bool st = (t + 1 < NKT);             // stage tile t+1 this group
    const unsigned short* sb  = lds + (t & 1) * 32768;
    const unsigned short* sbB = sb + 16384;
    bf16x8 bfr[4][2];
    #pragma unroll
    for (int p = 0; p < 4; ++p) {
      if (p == 0) {
        #pragma unroll
        for (int n = 0; n < 4; ++n)
          #pragma unroll
          for (int kk = 0; kk < 2; ++kk)
            bfr[n][kk] = *(const bf16x8*)(sbB + (wc * 64 + n * 16 + fr) * 64 +
                                          (((kk * 4 + fg) ^ rsw) * 8));
      }
      bf16x8 afr[2][2];
      #pragma unroll
      for (int mi = 0; mi < 2; ++mi)
        #pragma unroll
        for (int kk = 0; kk < 2; ++kk)
          afr[mi][kk] = *(const bf16x8*)(sb + (wr * 128 + (2 * p + mi) * 16 + fr) * 64 +
                                         (((kk * 4 + fg) ^ rsw) * 8));
      if (st) {
        if (p < 2) { BLOAD(t + 1, 2 * p);     BLOAD(t + 1, 2 * p + 1); }
        else       { ALOAD(t + 1, 2 * p - 4); ALOAD(t + 1, 2 * p - 3); }
      }
      __builtin_amdgcn_sched_barrier(0);
      __builtin_amdgcn_s_barrier();
      asm volatile("s_waitcnt lgkmcnt(0)" ::: "memory");
      __builtin_amdgcn_sched_barrier(0);
      __builtin_amdgcn_s_setprio(1);
      #pragma unroll
      for (int kk = 0; kk < 2; ++kk)
        #pragma unroll
        for (int mi = 0; mi < 2; ++mi)
          #pragma unroll
          for (int n = 0; n < 4; ++n)
            acc[2 * p + mi][n] = __builtin_amdgcn_mfma_f32_16x16x32_bf16(
                afr[mi][kk], bfr[n][kk], acc[2 * p + mi][n], 0, 0, 0);
      __builtin_amdgcn_s_setprio(0);
      __builtin_amdgcn_sched_barrier(0);
      if (p == 1) { if (st) { WAITV(4); } else { WAITV(0); } }
      if (p == 3 && st) { WAITV(2); }
      __builtin_amdgcn_s_barrier();
    }
  }

  // epilogue
  float bvals[4];
#pragma unroll
  for (int n = 0; n < 4; ++n) bvals[n] = bias[bcol + wc * 64 + n * 16 + fr];

  if (MODE == 0) {
    // head-major scatter: sec/h are wave-uniform; rows need b=row/77, s=row%77
    const int h64 = (bcol + wc * 64) >> 6;      // 0..35
    const int sec = h64 / NHEAD;                // 0:Q 1:K 2:V
    const int hh  = h64 - sec * NHEAD;
    const float scale = (sec == 0) ? 0.125f : 1.0f;
    unsigned short* outb = (unsigned short*)Cout + (size_t)sec * SECSZ;
#pragma unroll
    for (int m = 0; m < 8; ++m) {
#pragma unroll
      for (int r = 0; r < 4; ++r) {
        const int row = brow + wr * 128 + m * 16 + fg * 4 + r;
        const int bb = row / S_LEN;             // const-divide -> magic mul
        const int ss = row - bb * S_LEN;
        const size_t rbase = ((size_t)(bb * NHEAD + hh) * S_LEN + ss) * DHEAD;
#pragma unroll
        for (int n = 0; n < 4; ++n)
          outb[rbase + n * 16 + fr] = f2bf((acc[m][n][r] + bvals[n]) * scale);
      }
    }
  } else {
#pragma unroll
    for (int m = 0; m < 8; ++m) {
#pragma unroll
      for (int r = 0; r < 4; ++r) {
        const int row = brow + wr * 128 + m * 16 + fg * 4 + r;
#pragma unroll
        for (int n = 0; n < 4; ++n) {
          const int col = bcol + wc * 64 + n * 16 + fr;
          ((float*)Cout)[(size_t)row * EMB + col] = acc[m][n][r] + bvals[n];
        }
      }
    }
  }
}

// ---------------- attention: one block per (b,h), 5 waves (16-row stripes) ----
// Head-major Q/K/V: per-head working set = three contiguous 9.9 KB tiles.
// Q,K direct to regs (coalesced 128B-stride reads); V transposed through LDS
// (128B-contiguous row reads). ONE __syncthreads. LDS 30 KB -> 5 blocks/CU.
#define SV 104
__global__ __launch_bounds__(320) void attn_kernel(const unsigned short* __restrict__ qkv,
                                                   unsigned short* __restrict__ attn_out) {
  __shared__ unsigned short vT_lds[64 * SV];   // [d][t], stride 104
  __shared__ unsigned short p_lds[80 * SV];    // [s][t], stride 104

  const int tid  = threadIdx.x;
  const int wv_  = tid >> 6;   // stripe 0..4
  const int lane = tid & 63;
  const int fr = lane & 15;
  const int fg = lane >> 4;

  const int bh = blockIdx.x;
  const int b  = bh / NHEAD;

  const unsigned short* Qb = qkv;
  const unsigned short* Kb = qkv + SECSZ;
  const unsigned short* Vb = qkv + 2 * (size_t)SECSZ;
  const size_t hbase = (size_t)bh * (S_LEN * DHEAD);   // head tile base (in shorts)

  // Q fragments (this stripe's rows) + K fragments (all t rows) direct to regs
  bf16x8 qfr[2], kfr[5][2];
  {
    const int srow = wv_ * 16 + fr;
    const int qs = (srow < S_LEN) ? srow : 0;   // clamp: pad rows discarded later
    const unsigned short* qg = Qb + hbase + qs * DHEAD + fg * 8;
    qfr[0] = *(const bf16x8*)(qg);
    qfr[1] = *(const bf16x8*)(qg + 32);
    const unsigned short* kg = Kb + hbase + fg * 8;
#pragma unroll
    for (int n = 0; n < 5; ++n)
#pragma unroll
      for (int kk = 0; kk < 2; ++kk)
        kfr[n][kk] = *(const bf16x8*)(kg + (n * 16 + fr) * DHEAD + kk * 32);
    // t=77..79 for the last head reads past Kb into Vb: in-bounds, masked.
  }

  // zero ONLY the pad strips PV multiplies by nonzero values
  for (int i = tid; i < 64 * 19; i += 320) {
    int d = i / 19, c = 77 + (i - d * 19);
    vT_lds[d * SV + c] = 0;
  }
  for (int i = tid; i < 80 * 16; i += 320) {
    int s = i >> 4, c = 80 + (i & 15);
    p_lds[s * SV + c] = 0;
  }

  // stage transposed V: contiguous 128B row reads
  for (int idx = tid; idx < S_LEN * 32; idx += 320) {
    int s = idx >> 5, c = idx & 31;
    unsigned int vx = *(const unsigned int*)(Vb + hbase + s * DHEAD + c * 2);
    vT_lds[(c * 2 + 0) * SV + s] = (unsigned short)(vx & 0xffffu);
    vT_lds[(c * 2 + 1) * SV + s] = (unsigned short)(vx >> 16);
  }

  // QK^T : scores[s][t] from registers only — no barrier needed
  f32x4 sc[5];
#pragma unroll
  for (int n = 0; n < 5; ++n) sc[n] = (f32x4){0.f, 0.f, 0.f, 0.f};
#pragma unroll
  for (int kk = 0; kk < 2; ++kk)
#pragma unroll
    for (int n = 0; n < 5; ++n)
      sc[n] = __builtin_amdgcn_mfma_f32_16x16x32_bf16(qfr[kk], kfr[n][kk], sc[n], 0, 0, 0);

  // causal softmax; rows per lane: s = wv_*16 + fg*4 + r, cols t = n*16 + fr
  float mrow[4], ssum[4];
#pragma unroll
  for (int r = 0; r < 4; ++r) {
    const int s_loc = wv_ * 16 + fg * 4 + r;
    float mx = -1e30f;
#pragma unroll
    for (int n = 0; n < 5; ++n) {
      const int t = n * 16 + fr;
      float val = ((t <= s_loc) && (t < S_LEN)) ? sc[n][r] : -1e30f;
      sc[n][r] = val;
      mx = fmaxf(mx, val);
    }
    mrow[r] = mx;
  }
#pragma unroll
  for (int off = 1; off < 16; off <<= 1)
#pragma unroll
    for (int r = 0; r < 4; ++r)
      mrow[r] = fmaxf(mrow[r], __shfl_xor(mrow[r], off, 64));
#pragma unroll
  for (int r = 0; r < 4; ++r) {
    float sm = 0.f;
#pragma unroll
    for (int n = 0; n < 5; ++n) {
      float p = __expf(sc[n][r] - mrow[r]);
      sc[n][r] = p;
      sm += p;
    }
    ssum[r] = sm;
  }
#pragma unroll
  for (int off = 1; off < 16; off <<= 1)
#pragma unroll
    for (int r = 0; r < 4; ++r)
      ssum[r] += __shfl_xor(ssum[r], off, 64);

#pragma unroll
  for (int r = 0; r < 4; ++r) {
    const int srow = wv_ * 16 + fg * 4 + r;
    const float inv = 1.0f / ssum[r];
#pragma unroll
    for (int n = 0; n < 5; ++n)
      p_lds[srow * SV + n * 16 + fr] = f2bf(sc[n][r] * inv);
  }
  // ONE barrier: vT (cross-wave) + p (wave-local) both complete before PV
  __syncthreads();

  // PV : out[s][d] = sum_t p[s][t] * v[t][d], t padded to 96 (pad strips zero)
  f32x4 o[4];
#pragma unroll
  for (int n = 0; n < 4; ++n) o[n] = (f32x4){0.f, 0.f, 0.f, 0.f};
#pragma unroll
  for (int kk = 0; kk < 96; kk += 32) {
    bf16x8 afr = *(const bf16x8*)(p_lds + (wv_ * 16 + fr) * SV + kk + fg * 8);
#pragma unroll
    for (int n = 0; n < 4; ++n) {
      bf16x8 bfr = *(const bf16x8*)(vT_lds + (n * 16 + fr) * SV + kk + fg * 8);
      o[n] = __builtin_amdgcn_mfma_f32_16x16x32_bf16(afr, bfr, o[n], 0, 0, 0);
    }
  }

  // attn_o stays row-major [b*77+s][EMB] (what the out-GEMM expects)
  const int h = bh - b * NHEAD;
  const size_t obase = (size_t)b * S_LEN * EMB + (size_t)h * DHEAD;
#pragma unroll
  for (int r = 0; r < 4; ++r) {
    const int srow = wv_ * 16 + fg * 4 + r;
    if (srow < S_LEN) {
#pragma unroll
      for (int n = 0; n < 4; ++n)
        attn_out[obase + (size_t)srow * EMB + n * 16 + fr] = f2bf(o[n][r]);
    }
  }
}

extern "C" void kernel_launch(void* const* d_in, const int* in_sizes, int n_in,
                              void* d_out, int out_size, void* d_ws, size_t ws_size,
                              hipStream_t stream) {
  const float* x  = (const float*)d_in[0];
  const float* wq = (const float*)d_in[1];
  const float* bq = (const float*)d_in[2];
  const float* wk = (const float*)d_in[3];
  const float* bk = (const float*)d_in[4];
  const float* wv = (const float*)d_in[5];
  const float* bv = (const float*)d_in[6];
  const float* wo = (const float*)d_in[7];
  const float* bo = (const float*)d_in[8];
  (void)in_sizes; (void)n_in; (void)out_size; (void)ws_size;

  char* ws = (char*)d_ws;
  // layout (bytes):
  unsigned short* x_bf   = (unsigned short*)(ws);                  // M*E bf16      = 60,555,264
  unsigned short* wqkvT  = (unsigned short*)(ws + 60555264ULL);    // 2304*768 bf16 =  3,538,944
  unsigned short* woT    = (unsigned short*)(ws + 64094208ULL);    // 768*768 bf16  =  1,179,648
  float*          bqkv   = (float*)         (ws + 65273856ULL);    // 2304 f32      =      9,216
  unsigned short* qkv    = (unsigned short*)(ws + 65283072ULL);    // 3 sections    = 181,665,792
  unsigned short* attn_o = (unsigned short*)(ws + 246948864ULL);   // M*768 bf16    = 60,555,264

  prep_all<<<2048, 256, 0, stream>>>((const float4*)x, (ushort4*)x_bf,
                                     wq, wk, wv, wo, bq, bk, bv, wqkvT, woT, bqkv);
  gemm256<0><<<dim3(NQKV / 256, MROWS / 256), 512, 0, stream>>>(x_bf, wqkvT, bqkv, qkv);
  attn_kernel<<<BATCH * NHEAD, 320, 0, stream>>>(qkv, attn_o);
  gemm256<1><<<dim3(EMB / 256, MROWS / 256), 512, 0, stream>>>(attn_o, woT, bo, d_out);
}